// Round 2
// baseline (343.542 us; speedup 1.0000x reference)
//
#include <hip/hip_runtime.h>
#include <hip/hip_bf16.h>
#include <stdint.h>

typedef __bf16 bf16_t;
typedef __attribute__((ext_vector_type(8))) __bf16 bf16x8;
typedef __attribute__((ext_vector_type(4))) __bf16 bf16x4;
typedef __attribute__((ext_vector_type(4))) float f32x4;

#define DEVI __device__ __forceinline__

DEVI void gll16(const void* g, void* lds_base_wave_uniform) {
  __builtin_amdgcn_global_load_lds(
      (const __attribute__((address_space(1))) uint32_t*)(uintptr_t)g,
      (__attribute__((address_space(3))) uint32_t*)(uintptr_t)lds_base_wave_uniform,
      16, 0, 0);
}

// ---------------- fp32 -> bf16 convert (vectorized) ----------------
__global__ void cvt_f32_to_bf16(const float* __restrict__ src, bf16_t* __restrict__ dst, int n) {
  int i = (blockIdx.x * blockDim.x + threadIdx.x) * 4;
  if (i >= n) return;
  float4 v = *(const float4*)(src + i);
  bf16x4 o = {(bf16_t)v.x, (bf16_t)v.y, (bf16_t)v.z, (bf16_t)v.w};
  *(bf16x4*)(dst + i) = o;
}

// ---------------- t-shift: shift[b][n] = dot(t[b,:256], Wt_sel[n_local,:]) -----
__global__ void shift_kernel(const float* __restrict__ t,
                             const float* __restrict__ wtq,
                             const float* __restrict__ wtk,
                             const float* __restrict__ wtv,
                             float* __restrict__ shift) {
  int idx = blockIdx.x * blockDim.x + threadIdx.x;
  if (idx >= 8 * 2304) return;
  int b = idx / 2304, n = idx % 2304;
  const float* w = (n < 768) ? (wtq + (size_t)n * 256)
                 : (n < 1536) ? (wtk + (size_t)(n - 768) * 256)
                              : (wtv + (size_t)(n - 1536) * 256);
  const float4* tv = (const float4*)(t + (size_t)b * 256);
  const float4* wv = (const float4*)w;
  float acc = 0.f;
#pragma unroll 8
  for (int i = 0; i < 64; i++) {
    float4 a = tv[i], c = wv[i];
    acc += a.x * c.x + a.y * c.y + a.z * c.z + a.w * c.w;
  }
  shift[idx] = acc;
}

// ---------------- GEMM: C[m,n] = sum_k A[m,k]*B[n,k] (+add) -------------------
// A [M,K] bf16 row-major, B [N,K] bf16 row-major. M,N % 128 == 0, K % 32 == 0.
// MODE 0: C bf16, add = shift[8][N] indexed by batch (m>>10).
// MODE 1: C fp32, add = bias[N].
template <int MODE>
__global__ __launch_bounds__(256, 2) void gemm_bt(
    const bf16_t* __restrict__ A, const bf16_t* __restrict__ B,
    const float* __restrict__ add, void* __restrict__ Cout,
    int M, int N, int K) {
  __shared__ alignas(16) bf16_t As[128 * 32];
  __shared__ alignas(16) bf16_t Bs[128 * 32];
  const int t = threadIdx.x, l = t & 63, w = t >> 6;
  const int wr = w >> 1, wc = w & 1;
  const int bm = blockIdx.x, bn = blockIdx.y;

  f32x4 acc[4][4] = {};

  const int srow = t >> 2;
  const int scol = (t & 3) * 8;
  const bf16_t* Ab = A + ((size_t)bm * 128 + srow) * K + scol;
  const bf16_t* Bb = B + ((size_t)bn * 128 + srow) * K + scol;
  char* AsB = (char*)As + w * 1024;
  char* BsB = (char*)Bs + w * 1024;
  const size_t K64 = (size_t)64 * K;

  const int ro = (l & 15) * 32 + (l >> 4) * 8;
  const bf16_t* ApA = As + (wr * 64) * 32 + ro;
  const bf16_t* BpB = Bs + (wc * 64) * 32 + ro;

  for (int k0 = 0; k0 < K; k0 += 32) {
    __syncthreads();
    gll16(Ab + k0, AsB);
    gll16(Ab + K64 + k0, AsB + 4096);
    gll16(Bb + k0, BsB);
    gll16(Bb + K64 + k0, BsB + 4096);
    __syncthreads();
    bf16x8 af[4], bfr[4];
#pragma unroll
    for (int i = 0; i < 4; i++) {
      af[i]  = *(const bf16x8*)(ApA + i * 16 * 32);
      bfr[i] = *(const bf16x8*)(BpB + i * 16 * 32);
    }
#pragma unroll
    for (int mi = 0; mi < 4; mi++)
#pragma unroll
      for (int ni = 0; ni < 4; ni++)
        acc[mi][ni] = __builtin_amdgcn_mfma_f32_16x16x32_bf16(af[mi], bfr[ni], acc[mi][ni], 0, 0, 0);
  }

  const int row0 = bm * 128 + wr * 64 + (l >> 4) * 4;
  const int col0 = bn * 128 + wc * 64 + (l & 15);
  if (MODE == 0) {
    bf16_t* C = (bf16_t*)Cout;
    const float* sh = add + (size_t)((bm * 128) >> 10) * N;
#pragma unroll
    for (int ni = 0; ni < 4; ni++) {
      const int col = col0 + ni * 16;
      const float s0 = sh[col];
#pragma unroll
      for (int mi = 0; mi < 4; mi++)
#pragma unroll
        for (int i = 0; i < 4; i++)
          C[(size_t)(row0 + mi * 16 + i) * N + col] = (bf16_t)(acc[mi][ni][i] + s0);
    }
  } else {
    float* C = (float*)Cout;
#pragma unroll
    for (int ni = 0; ni < 4; ni++) {
      const int col = col0 + ni * 16;
      const float s0 = add[col];
#pragma unroll
      for (int mi = 0; mi < 4; mi++)
#pragma unroll
        for (int i = 0; i < 4; i++)
          C[(size_t)(row0 + mi * 16 + i) * N + col] = acc[mi][ni][i] + s0;
    }
  }
}

// ---------------- fused flash attention with additive bias --------------------
// qkv [8][1024][2304] bf16 (q|k|v each 768 = 12 heads * 64)
// bias [12][1024][1024] bf16 ; o [8][1024][768] bf16
// grid (16 qtiles, 12 heads, 8 batches), 256 threads (4 waves, 16 q-rows each)
__global__ __launch_bounds__(256, 2) void attn_fused(
    const bf16_t* __restrict__ qkv,
    const bf16_t* __restrict__ bias,
    bf16_t* __restrict__ o) {
  const int qt = blockIdx.x, h = blockIdx.y, b = blockIdx.z;
  const int t = threadIdx.x, l = t & 63, w = t >> 6;

  __shared__ alignas(16) bf16_t Ks[64 * 64];
  __shared__ alignas(16) bf16_t Vt[64 * 64];
  __shared__ alignas(16) bf16_t Bi[64 * 64];
  __shared__ alignas(16) bf16_t Ps[4][16 * 64];

  const size_t rowb = (size_t)b * 1024;

  // Q fragments (A operand): row = l&15 within wave tile, 2 k-chunks of 32
  bf16x8 qf[2];
  {
    const bf16_t* qp = qkv + (rowb + qt * 64 + w * 16 + (l & 15)) * 2304 + h * 64 + (l >> 4) * 8;
    qf[0] = *(const bf16x8*)qp;
    qf[1] = *(const bf16x8*)(qp + 32);
  }

  float m_run[4] = {-INFINITY, -INFINITY, -INFINITY, -INFINITY};
  float l_run[4] = {0.f, 0.f, 0.f, 0.f};
  f32x4 oacc[4] = {};

  const int sr = t >> 3;  // 0..31: LDS row within stage half
  const int sc = t & 7;   // 16B chunk within row
  char* KsB = (char*)Ks + w * 1024;
  char* BiB = (char*)Bi + w * 1024;
  const float LOG2E = 1.44269504088896f;

  for (int kt = 0; kt < 16; kt++) {
    __syncthreads();
    // stage K and bias tiles: linear LDS dest, inverse-swizzled global source
#pragma unroll
    for (int s = 0; s < 2; s++) {
      const int r = s * 32 + sr;
      const int gc = (sc ^ (r & 7)) * 8;
      gll16(qkv + (rowb + kt * 64 + r) * 2304 + 768 + h * 64 + gc, KsB + s * 4096);
      gll16(bias + ((size_t)h * 1024 + qt * 64 + r) * 1024 + kt * 64 + gc, BiB + s * 4096);
    }
    // stage V transposed (Vt[d][kp]) with the same chunk swizzle
    {
      const bf16_t* vp = qkv + (rowb + kt * 64 + l) * 2304 + 1536 + h * 64 + w * 16;
      bf16x8 v0 = *(const bf16x8*)vp;
      bf16x8 v1 = *(const bf16x8*)(vp + 8);
#pragma unroll
      for (int j = 0; j < 16; j++) {
        const int d = w * 16 + j;
        const int addr = d * 64 + (((l >> 3) ^ (d & 7)) * 8) + (l & 7);
        Vt[addr] = (j < 8) ? v0[j] : v1[j - 8];
      }
    }
    __syncthreads();

    // S = Q K^T  (C layout: col kp = l&15, row q = (l>>4)*4 + reg)
    f32x4 sv[4];
#pragma unroll
    for (int nf = 0; nf < 4; nf++) {
      const int kp = nf * 16 + (l & 15);
      const bf16_t* kb = Ks + kp * 64;
      bf16x8 kf0 = *(const bf16x8*)(kb + (((l >> 4) ^ (kp & 7)) * 8));
      bf16x8 kf1 = *(const bf16x8*)(kb + ((((l >> 4) + 4) ^ (kp & 7)) * 8));
      f32x4 z = {0.f, 0.f, 0.f, 0.f};
      z = __builtin_amdgcn_mfma_f32_16x16x32_bf16(qf[0], kf0, z, 0, 0, 0);
      z = __builtin_amdgcn_mfma_f32_16x16x32_bf16(qf[1], kf1, z, 0, 0, 0);
      sv[nf] = z;
    }

    // bias add + wave-parallel online softmax (reduce over 16 lanes)
    float p[4][4];
    float alpha[4];
#pragma unroll
    for (int i = 0; i < 4; i++) {
      const int r = w * 16 + (l >> 4) * 4 + i;  // local q row 0..63
      float lg[4];
#pragma unroll
      for (int nf = 0; nf < 4; nf++) {
        const int kp = nf * 16 + (l & 15);
        const int ba = r * 64 + (((kp >> 3) ^ (r & 7)) * 8) + (kp & 7);
        lg[nf] = sv[nf][i] * 0.125f + (float)Bi[ba];
      }
      float mx = fmaxf(fmaxf(lg[0], lg[1]), fmaxf(lg[2], lg[3]));
      mx = fmaxf(mx, __shfl_xor(mx, 1));
      mx = fmaxf(mx, __shfl_xor(mx, 2));
      mx = fmaxf(mx, __shfl_xor(mx, 4));
      mx = fmaxf(mx, __shfl_xor(mx, 8));
      const float mnew = fmaxf(m_run[i], mx);
      alpha[i] = exp2f((m_run[i] - mnew) * LOG2E);
      m_run[i] = mnew;
      float rs = 0.f;
#pragma unroll
      for (int nf = 0; nf < 4; nf++) {
        p[nf][i] = exp2f((lg[nf] - mnew) * LOG2E);
        rs += p[nf][i];
      }
      rs += __shfl_xor(rs, 1);
      rs += __shfl_xor(rs, 2);
      rs += __shfl_xor(rs, 4);
      rs += __shfl_xor(rs, 8);
      l_run[i] = l_run[i] * alpha[i] + rs;
    }

    // P -> LDS (bf16, swizzled); rescale O
    bf16_t* Pw = Ps[w];
#pragma unroll
    for (int nf = 0; nf < 4; nf++)
#pragma unroll
      for (int i = 0; i < 4; i++) {
        const int rq = (l >> 4) * 4 + i;
        const int kp = nf * 16 + (l & 15);
        Pw[rq * 64 + (((kp >> 3) ^ (rq & 7)) * 8) + (kp & 7)] = (bf16_t)p[nf][i];
      }
#pragma unroll
    for (int nf2 = 0; nf2 < 4; nf2++)
#pragma unroll
      for (int i = 0; i < 4; i++)
        oacc[nf2][i] *= alpha[i];

    // O += P V
    bf16x8 pf[2];
#pragma unroll
    for (int kc = 0; kc < 2; kc++) {
      const int rq = l & 15;
      const int chunk = kc * 4 + (l >> 4);
      pf[kc] = *(const bf16x8*)(Pw + rq * 64 + ((chunk ^ (rq & 7)) * 8));
    }
#pragma unroll
    for (int nf2 = 0; nf2 < 4; nf2++) {
      const int d = nf2 * 16 + (l & 15);
      const bf16_t* vb = Vt + d * 64;
      bf16x8 vf0 = *(const bf16x8*)(vb + (((l >> 4) ^ (d & 7)) * 8));
      bf16x8 vf1 = *(const bf16x8*)(vb + ((((l >> 4) + 4) ^ (d & 7)) * 8));
      oacc[nf2] = __builtin_amdgcn_mfma_f32_16x16x32_bf16(pf[0], vf0, oacc[nf2], 0, 0, 0);
      oacc[nf2] = __builtin_amdgcn_mfma_f32_16x16x32_bf16(pf[1], vf1, oacc[nf2], 0, 0, 0);
    }
  }

  // normalize + store merged-head output
#pragma unroll
  for (int i = 0; i < 4; i++) {
    const float inv = 1.0f / l_run[i];
    const size_t row = rowb + qt * 64 + w * 16 + (l >> 4) * 4 + i;
#pragma unroll
    for (int nf2 = 0; nf2 < 4; nf2++)
      o[row * 768 + h * 64 + nf2 * 16 + (l & 15)] = (bf16_t)(oacc[nf2][i] * inv);
  }
}

// ------------------------------- launcher ------------------------------------
extern "C" void kernel_launch(void* const* d_in, const int* in_sizes, int n_in,
                              void* d_out, int out_size, void* d_ws, size_t ws_size,
                              hipStream_t stream) {
  const float* x    = (const float*)d_in[0];
  const float* tin  = (const float*)d_in[1];
  const float* bias = (const float*)d_in[2];
  const float* Wxq  = (const float*)d_in[3];
  const float* Wxk  = (const float*)d_in[4];
  const float* Wxv  = (const float*)d_in[5];
  const float* Wtq  = (const float*)d_in[6];
  const float* Wtk  = (const float*)d_in[7];
  const float* Wtv  = (const float*)d_in[8];
  const float* Wo   = (const float*)d_in[9];
  const float* bo   = (const float*)d_in[10];
  float* out = (float*)d_out;

  char* ws = (char*)d_ws;
  bf16_t* x_bf    = (bf16_t*)(ws);                 // 8192*768*2      = 12,582,912
  bf16_t* wcat    = (bf16_t*)(ws + 12582912);      // 2304*768*2     =  3,538,944
  bf16_t* wo_bf   = (bf16_t*)(ws + 16121856);      // 768*768*2      =  1,179,648
  bf16_t* bias_bf = (bf16_t*)(ws + 17301504);      // 12*1024*1024*2 = 25,165,824
  float*  shift   = (float*) (ws + 42467328);      // 8*2304*4       =     73,728
  bf16_t* qkvb    = (bf16_t*)(ws + 42541056);      // 8192*2304*2    = 37,748,736
  bf16_t* obuf    = (bf16_t*)(ws + 80289792);      // 8192*768*2     = 12,582,912
  // total 92,872,704 bytes

  const int W = 768 * 768;
  // converts
  cvt_f32_to_bf16<<<6144, 256, 0, stream>>>(x, x_bf, 8192 * 768);
  cvt_f32_to_bf16<<<576, 256, 0, stream>>>(Wxq, wcat, W);
  cvt_f32_to_bf16<<<576, 256, 0, stream>>>(Wxk, wcat + W, W);
  cvt_f32_to_bf16<<<576, 256, 0, stream>>>(Wxv, wcat + 2 * W, W);
  cvt_f32_to_bf16<<<576, 256, 0, stream>>>(Wo, wo_bf, W);
  cvt_f32_to_bf16<<<12288, 256, 0, stream>>>(bias, bias_bf, 12 * 1024 * 1024);
  // time shifts
  shift_kernel<<<72, 256, 0, stream>>>(tin, Wtq, Wtk, Wtv, shift);
  // fused QKV projection
  gemm_bt<0><<<dim3(64, 18), 256, 0, stream>>>(x_bf, wcat, shift, qkvb, 8192, 2304, 768);
  // attention
  attn_fused<<<dim3(16, 12, 8), 256, 0, stream>>>(qkvb, bias_bf, obuf);
  // output projection (fp32 out + b_o)
  gemm_bt<1><<<dim3(64, 6), 256, 0, stream>>>(obuf, wo_bf, bo, out, 8192, 768, 768);
}